// Round 1
// baseline (697.276 us; speedup 1.0000x reference)
//
#include <hip/hip_runtime.h>
#include <hip/hip_bf16.h>
#include <cstdint>
#include <cstddef>

// BitNet b1.58 attention block: B=2 S=2048 D=2048 H=16 HD=128.
// All quantized matmuls done in bf16 MFMA (exact: int8 x ternary, sums < 2^24).

#define BB 2
#define SS 2048
#define DD 2048
#define HH 16
#define HDD 128
#define MM (BB*SS)   // 4096 token rows

typedef __attribute__((ext_vector_type(8))) short bf16x8;
typedef __attribute__((ext_vector_type(4))) float f32x4;
typedef unsigned short u16;
typedef unsigned int   u32;

#define MFMA(a,b,c) __builtin_amdgcn_mfma_f32_16x16x32_bf16(a,b,c,0,0,0)

static __device__ __forceinline__ u16 f2bf(float f) {
  // round-to-nearest-even float->bf16 (no NaN inputs here)
  u32 x = __float_as_uint(f);
  u32 r = x + 0x7fffu + ((x >> 16) & 1u);
  return (u16)(r >> 16);
}

// ---------------- weight scale: deterministic two-stage |w| mean in f64 ----
__global__ void k_wabs_partial(const float* __restrict__ w0, const float* __restrict__ w1,
                               const float* __restrict__ w2, const float* __restrict__ w3,
                               double* __restrict__ part) {
  int m = blockIdx.x >> 8, blk = blockIdx.x & 255;
  const float* w = (m == 0) ? w0 : (m == 1) ? w1 : (m == 2) ? w2 : w3;
  const float* p = w + (size_t)blk * 16384;
  double s = 0.0;
  for (int i = threadIdx.x * 4; i < 16384; i += 1024) {
    float4 v = *(const float4*)(p + i);
    s += (double)fabsf(v.x) + (double)fabsf(v.y) + (double)fabsf(v.z) + (double)fabsf(v.w);
  }
  __shared__ double red[256];
  red[threadIdx.x] = s;
  __syncthreads();
  for (int off = 128; off > 0; off >>= 1) {
    if ((int)threadIdx.x < off) red[threadIdx.x] += red[threadIdx.x + off];
    __syncthreads();
  }
  if (threadIdx.x == 0) part[m * 256 + blk] = red[0];
}

__global__ void k_wscale_final(const double* __restrict__ part, float* __restrict__ scales) {
  int m = threadIdx.x;
  if (m < 4) {
    double s = 0.0;
    for (int i = 0; i < 256; i++) s += part[m * 256 + i];
    float v = (float)(s * (1.0 / 4194304.0));   // /(D*D), power of 2: exact
    scales[m] = fmaxf(v, 1e-6f);
  }
}

// ---------------- ternary weight quant -> bf16 ------------------------------
__global__ void k_wquant(const float* __restrict__ w0, const float* __restrict__ w1,
                         const float* __restrict__ w2, const float* __restrict__ w3,
                         u16* __restrict__ wq, const float* __restrict__ scales) {
  int m = blockIdx.y;
  const float* w = (m == 0) ? w0 : (m == 1) ? w1 : (m == 2) ? w2 : w3;
  float ws = scales[m];
  size_t i = ((size_t)blockIdx.x * 256 + threadIdx.x) * 4;
  float4 v = *(const float4*)(w + i);
  u16* o = wq + (size_t)m * DD * DD + i;
  float a = fminf(1.f, fmaxf(-1.f, rintf(v.x / ws)));
  float b = fminf(1.f, fmaxf(-1.f, rintf(v.y / ws)));
  float c = fminf(1.f, fmaxf(-1.f, rintf(v.z / ws)));
  float d = fminf(1.f, fmaxf(-1.f, rintf(v.w / ws)));
  ushort4 pk;
  pk.x = f2bf(a); pk.y = f2bf(b); pk.z = f2bf(c); pk.w = f2bf(d);
  *(ushort4*)o = pk;
}

// ---------------- per-token absmax + inv scale ------------------------------
__global__ void k_rowamax(const float* __restrict__ x, float* __restrict__ amax,
                          float* __restrict__ sinv) {
  int row = blockIdx.x;
  const float* p = x + (size_t)row * DD;
  float m = 0.f;
  for (int i = threadIdx.x * 4; i < DD; i += 1024) {
    float4 v = *(const float4*)(p + i);
    m = fmaxf(m, fmaxf(fmaxf(fabsf(v.x), fabsf(v.y)), fmaxf(fabsf(v.z), fabsf(v.w))));
  }
  m = fmaxf(m, __shfl_xor(m, 1));  m = fmaxf(m, __shfl_xor(m, 2));
  m = fmaxf(m, __shfl_xor(m, 4));  m = fmaxf(m, __shfl_xor(m, 8));
  m = fmaxf(m, __shfl_xor(m, 16)); m = fmaxf(m, __shfl_xor(m, 32));
  __shared__ float red[4];
  if ((threadIdx.x & 63) == 0) red[threadIdx.x >> 6] = m;
  __syncthreads();
  if (threadIdx.x == 0) {
    m = fmaxf(fmaxf(red[0], red[1]), fmaxf(red[2], red[3]));
    m = fmaxf(m, 1e-8f);            // clip(amax, 1e-8)
    amax[row] = m;
    sinv[row] = 127.0f / m;         // matches ref: QMAX / a_max
  }
}

// ---------------- int8-range activation quant -> bf16 -----------------------
__global__ void k_aquant(const float* __restrict__ x, u16* __restrict__ xq,
                         const float* __restrict__ sinv) {
  size_t i = ((size_t)blockIdx.x * 256 + threadIdx.x) * 4;
  int row = (int)(i >> 11);  // /2048
  float s = sinv[row];
  float4 v = *(const float4*)(x + i);
  float a = fminf(127.f, fmaxf(-127.f, rintf(v.x * s)));
  float b = fminf(127.f, fmaxf(-127.f, rintf(v.y * s)));
  float c = fminf(127.f, fmaxf(-127.f, rintf(v.z * s)));
  float d = fminf(127.f, fmaxf(-127.f, rintf(v.w * s)));
  ushort4 pk;
  pk.x = f2bf(a); pk.y = f2bf(b); pk.z = f2bf(c); pk.w = f2bf(d);
  *(ushort4*)(xq + i) = pk;
}

// ---------------- bf16 MFMA GEMM: C[m][n] = sum_k A[m][k]*Bw[n][k] ----------
// 128x128 tile, BK=64, 4 waves (2x2), padded LDS stride 72 (2-way conflicts).
// Epilogue: y * (w_scale * amax[row] / 127); out bf16 (qkv) or f32 (final).
template<bool OB>
__global__ __launch_bounds__(256) void k_gemm(const u16* __restrict__ A, const u16* __restrict__ Bw,
                                              const float* __restrict__ amax,
                                              const float* __restrict__ scales, int sbase,
                                              void* __restrict__ outv) {
  const int LT = 72;
  __shared__ u16 As[128 * 72];
  __shared__ u16 Bs[128 * 72];
  int bm = blockIdx.x, bn = blockIdx.y, mz = blockIdx.z;
  const u16* Bm = Bw + (size_t)mz * DD * DD;
  float wsc = scales[sbase + mz];
  int t = threadIdx.x, w = t >> 6, l = t & 63;
  int wr = w >> 1, wc = w & 1;
  int l15 = l & 15, lh = l >> 4;
  int sr = t >> 3, scol = (t & 7) * 8;
  f32x4 acc[4][4] = {};
  for (int kb = 0; kb < DD / 64; kb++) {
    #pragma unroll
    for (int p = 0; p < 4; p++) {
      int r = p * 32 + sr;
      *(int4*)(As + r * LT + scol) = *(const int4*)(A  + (size_t)(bm * 128 + r) * DD + kb * 64 + scol);
      *(int4*)(Bs + r * LT + scol) = *(const int4*)(Bm + (size_t)(bn * 128 + r) * DD + kb * 64 + scol);
    }
    __syncthreads();
    #pragma unroll
    for (int ks = 0; ks < 2; ks++) {
      bf16x8 af[4], bfr[4];
      #pragma unroll
      for (int i = 0; i < 4; i++)
        af[i] = *(const bf16x8*)(As + (wr * 64 + i * 16 + l15) * LT + ks * 32 + lh * 8);
      #pragma unroll
      for (int j = 0; j < 4; j++)
        bfr[j] = *(const bf16x8*)(Bs + (wc * 64 + j * 16 + l15) * LT + ks * 32 + lh * 8);
      #pragma unroll
      for (int i = 0; i < 4; i++)
        #pragma unroll
        for (int j = 0; j < 4; j++)
          acc[i][j] = MFMA(af[i], bfr[j], acc[i][j]);
    }
    __syncthreads();
  }
  #pragma unroll
  for (int i = 0; i < 4; i++) {
    int row0 = bm * 128 + wr * 64 + i * 16 + lh * 4;
    #pragma unroll
    for (int r = 0; r < 4; r++) {
      float sc = (wsc * amax[row0 + r]) / 127.0f;
      #pragma unroll
      for (int j = 0; j < 4; j++) {
        int col = bn * 128 + wc * 64 + j * 16 + l15;
        float y = acc[i][j][r] * sc;
        if (OB) ((u16*)outv + (size_t)mz * MM * DD)[(size_t)(row0 + r) * DD + col] = f2bf(y);
        else    ((float*)outv)[(size_t)(row0 + r) * DD + col] = y;
      }
    }
  }
}

// ---------------- causal flash attention (bf16 MFMA, online softmax) --------
// grid (S/64, B*H), 256 thr (4 waves x 16 q-rows). K tile + transposed V tile
// in padded LDS; P routed through LDS for the PV A-operand.
__global__ __launch_bounds__(256) void k_attn(const u16* __restrict__ Q, const u16* __restrict__ K,
                                              const u16* __restrict__ V, float* __restrict__ O) {
  const int LKT = 136, LVT = 72, LPT = 72;
  __shared__ u16 Ks[64 * 136];
  __shared__ u16 Vt[128 * 72];
  __shared__ u16 Ps[64 * 72];
  int qb = blockIdx.x, bh = blockIdx.y;
  int b = bh >> 4, h = bh & 15;
  int t = threadIdx.x, w = t >> 6, l = t & 63;
  int l15 = l & 15, lh = l >> 4;
  size_t base = ((size_t)(b * SS)) * DD + h * HDD;
  bf16x8 qf[4];
  {
    int qrow = qb * 64 + w * 16 + l15;
    const u16* qp = Q + base + (size_t)qrow * DD + lh * 8;
    #pragma unroll
    for (int kt = 0; kt < 4; kt++) qf[kt] = *(const bf16x8*)(qp + kt * 32);
  }
  f32x4 cacc[8] = {};
  float mrun[4], lrun[4];
  #pragma unroll
  for (int r = 0; r < 4; r++) { mrun[r] = -INFINITY; lrun[r] = 0.f; }
  const float sc = 0.08838834764831845f;  // 1/sqrt(128)
  int krow = t >> 4, kcol = (t & 15) * 8;
  int hd = t & 127, sg = t >> 7;
  for (int kb = 0; kb <= qb; kb++) {
    #pragma unroll
    for (int p = 0; p < 4; p++) {
      int r = p * 16 + krow;
      *(int4*)(Ks + r * LKT + kcol) = *(const int4*)(K + base + (size_t)(kb * 64 + r) * DD + kcol);
    }
    #pragma unroll
    for (int p = 0; p < 4; p++) {   // V staged transposed: Vt[hd][s]
      int s0 = sg * 8 + p * 16;
      const u16* vp = V + base + (size_t)(kb * 64 + s0) * DD + hd;
      u32 a0 = (u32)vp[0]      | ((u32)vp[DD] << 16);
      u32 a1 = (u32)vp[2 * DD] | ((u32)vp[3 * DD] << 16);
      u32 a2 = (u32)vp[4 * DD] | ((u32)vp[5 * DD] << 16);
      u32 a3 = (u32)vp[6 * DD] | ((u32)vp[7 * DD] << 16);
      uint4 pk; pk.x = a0; pk.y = a1; pk.z = a2; pk.w = a3;
      *(uint4*)(Vt + hd * LVT + s0) = pk;
    }
    __syncthreads();
    // S = Q K^T (wave: 16 q-rows x 64 k-cols)
    f32x4 sf[4] = {};
    #pragma unroll
    for (int kt = 0; kt < 4; kt++) {
      #pragma unroll
      for (int nt = 0; nt < 4; nt++) {
        bf16x8 bfr = *(const bf16x8*)(Ks + (nt * 16 + l15) * LKT + kt * 32 + lh * 8);
        sf[nt] = MFMA(qf[kt], bfr, sf[nt]);
      }
    }
    bool diag = (kb == qb);
    #pragma unroll
    for (int nt = 0; nt < 4; nt++) {
      #pragma unroll
      for (int r = 0; r < 4; r++) {
        float v = sf[nt][r] * sc;
        if (diag && (nt * 16 + l15) > (w * 16 + lh * 4 + r)) v = -1e30f;
        sf[nt][r] = v;
      }
    }
    // online softmax: row stats across the 16-lane (l&15) group
    #pragma unroll
    for (int r = 0; r < 4; r++) {
      float mx = fmaxf(fmaxf(sf[0][r], sf[1][r]), fmaxf(sf[2][r], sf[3][r]));
      mx = fmaxf(mx, __shfl_xor(mx, 1)); mx = fmaxf(mx, __shfl_xor(mx, 2));
      mx = fmaxf(mx, __shfl_xor(mx, 4)); mx = fmaxf(mx, __shfl_xor(mx, 8));
      float mnew = fmaxf(mrun[r], mx);
      float alpha = __expf(mrun[r] - mnew);
      float s0 = 0.f;
      #pragma unroll
      for (int nt = 0; nt < 4; nt++) { float pv = __expf(sf[nt][r] - mnew); sf[nt][r] = pv; s0 += pv; }
      s0 += __shfl_xor(s0, 1); s0 += __shfl_xor(s0, 2);
      s0 += __shfl_xor(s0, 4); s0 += __shfl_xor(s0, 8);
      lrun[r] = lrun[r] * alpha + s0;
      mrun[r] = mnew;
      #pragma unroll
      for (int n2 = 0; n2 < 8; n2++) cacc[n2][r] *= alpha;
    }
    // P -> LDS (C-layout -> A-layout transpose), then PV
    #pragma unroll
    for (int r = 0; r < 4; r++)
      #pragma unroll
      for (int nt = 0; nt < 4; nt++)
        Ps[(w * 16 + lh * 4 + r) * LPT + nt * 16 + l15] = f2bf(sf[nt][r]);
    #pragma unroll
    for (int ks = 0; ks < 2; ks++) {
      bf16x8 pf = *(const bf16x8*)(Ps + (w * 16 + l15) * LPT + ks * 32 + lh * 8);
      #pragma unroll
      for (int n2 = 0; n2 < 8; n2++) {
        bf16x8 vf = *(const bf16x8*)(Vt + (n2 * 16 + l15) * LVT + ks * 32 + lh * 8);
        cacc[n2] = MFMA(pf, vf, cacc[n2]);
      }
    }
    __syncthreads();
  }
  #pragma unroll
  for (int r = 0; r < 4; r++) {
    float inv = 1.0f / lrun[r];
    int srow = qb * 64 + w * 16 + lh * 4 + r;
    float* op = O + base + (size_t)srow * DD;
    #pragma unroll
    for (int n2 = 0; n2 < 8; n2++) op[n2 * 16 + l15] = cacc[n2][r] * inv;
  }
}

// ---------------- launch ----------------------------------------------------
// ws layout (bytes), total ~134.4 MB:
//   0        scales (4 f32)        256      partials (1024 f64)
//   16384    amax_x   32768 sinv_x   49152 amax_ctx   65536 sinv_ctx
//   131072   w_q bf16 (4 x D*D)  = 33,554,432
//   33685504 x_q bf16 (M*D)      = 16,777,216   (reused as ctx_q)
//   50462720 q bf16 | 67239936 k | 84017152 v   (16,777,216 each)
//   100794368 ctx f32            = 33,554,432
extern "C" void kernel_launch(void* const* d_in, const int* in_sizes, int n_in,
                              void* d_out, int out_size, void* d_ws, size_t ws_size,
                              hipStream_t stream) {
  const float* x  = (const float*)d_in[0];
  const float* wq = (const float*)d_in[1];
  const float* wk = (const float*)d_in[2];
  const float* wv = (const float*)d_in[3];
  const float* wo = (const float*)d_in[4];
  char* ws = (char*)d_ws;
  float*  scales = (float*)(ws + 0);
  double* part   = (double*)(ws + 256);
  float*  amaxx  = (float*)(ws + 16384);
  float*  sxinv  = (float*)(ws + 32768);
  float*  amaxc  = (float*)(ws + 49152);
  float*  scinv  = (float*)(ws + 65536);
  u16*    wqq    = (u16*)(ws + 131072);
  u16*    xq     = (u16*)(ws + 33685504);   // reused as ctx_q
  u16*    qb     = (u16*)(ws + 50462720);
  u16*    kb     = (u16*)(ws + 67239936);
  u16*    vb     = (u16*)(ws + 84017152);
  float*  ctx    = (float*)(ws + 100794368);
  (void)in_sizes; (void)n_in; (void)out_size; (void)ws_size;

  k_wabs_partial<<<1024, 256, 0, stream>>>(wq, wk, wv, wo, part);
  k_wscale_final<<<1, 64, 0, stream>>>(part, scales);
  k_wquant<<<dim3(4096, 4), 256, 0, stream>>>(wq, wk, wv, wo, wqq, scales);
  k_rowamax<<<MM, 256, 0, stream>>>(x, amaxx, sxinv);
  k_aquant<<<8192, 256, 0, stream>>>(x, xq, sxinv);
  // q,k,v projections: out buffers are contiguous -> one launch, grid.z=3
  k_gemm<true><<<dim3(32, 16, 3), 256, 0, stream>>>(xq, wqq, amaxx, scales, 0, (void*)qb);
  k_attn<<<dim3(32, 32), 256, 0, stream>>>(qb, kb, vb, ctx);
  k_rowamax<<<MM, 256, 0, stream>>>(ctx, amaxc, scinv);
  k_aquant<<<8192, 256, 0, stream>>>(ctx, xq, scinv);  // ctx_q into xq buffer
  k_gemm<false><<<dim3(32, 16, 1), 256, 0, stream>>>(xq, wqq + (size_t)3 * DD * DD, amaxc, scales, 3, d_out);
}

// Round 2
// 537.346 us; speedup vs baseline: 1.2976x; 1.2976x over previous
//
#include <hip/hip_runtime.h>
#include <hip/hip_bf16.h>
#include <cstdint>
#include <cstddef>

// BitNet b1.58 attention block: B=2 S=2048 D=2048 H=16 HD=128.
// All quantized matmuls done in bf16 MFMA (exact: int8 x ternary, sums < 2^24).

#define BB 2
#define SS 2048
#define DD 2048
#define HH 16
#define HDD 128
#define MM (BB*SS)   // 4096 token rows

typedef __attribute__((ext_vector_type(8))) short bf16x8;
typedef __attribute__((ext_vector_type(4))) float f32x4;
typedef unsigned short u16;
typedef unsigned int   u32;

#define MFMA(a,b,c) __builtin_amdgcn_mfma_f32_16x16x32_bf16(a,b,c,0,0,0)

static __device__ __forceinline__ u16 f2bf(float f) {
  // round-to-nearest-even float->bf16 (no NaN inputs here)
  u32 x = __float_as_uint(f);
  u32 r = x + 0x7fffu + ((x >> 16) & 1u);
  return (u16)(r >> 16);
}

// ---------------- weight scale: deterministic two-stage |w| mean in f64 ----
__global__ void k_wabs_partial(const float* __restrict__ w0, const float* __restrict__ w1,
                               const float* __restrict__ w2, const float* __restrict__ w3,
                               double* __restrict__ part) {
  int m = blockIdx.x >> 8, blk = blockIdx.x & 255;
  const float* w = (m == 0) ? w0 : (m == 1) ? w1 : (m == 2) ? w2 : w3;
  const float* p = w + (size_t)blk * 16384;
  double s = 0.0;
  for (int i = threadIdx.x * 4; i < 16384; i += 1024) {
    float4 v = *(const float4*)(p + i);
    s += (double)fabsf(v.x) + (double)fabsf(v.y) + (double)fabsf(v.z) + (double)fabsf(v.w);
  }
  __shared__ double red[256];
  red[threadIdx.x] = s;
  __syncthreads();
  for (int off = 128; off > 0; off >>= 1) {
    if ((int)threadIdx.x < off) red[threadIdx.x] += red[threadIdx.x + off];
    __syncthreads();
  }
  if (threadIdx.x == 0) part[m * 256 + blk] = red[0];
}

__global__ void k_wscale_final(const double* __restrict__ part, float* __restrict__ scales) {
  int m = threadIdx.x;
  if (m < 4) {
    double s = 0.0;
    for (int i = 0; i < 256; i++) s += part[m * 256 + i];
    float v = (float)(s * (1.0 / 4194304.0));   // /(D*D), power of 2: exact
    scales[m] = fmaxf(v, 1e-6f);
  }
}

// ---------------- ternary weight quant -> bf16 ------------------------------
__global__ void k_wquant(const float* __restrict__ w0, const float* __restrict__ w1,
                         const float* __restrict__ w2, const float* __restrict__ w3,
                         u16* __restrict__ wq, const float* __restrict__ scales) {
  int m = blockIdx.y;
  const float* w = (m == 0) ? w0 : (m == 1) ? w1 : (m == 2) ? w2 : w3;
  float ws = scales[m];
  size_t i = ((size_t)blockIdx.x * 256 + threadIdx.x) * 4;
  float4 v = *(const float4*)(w + i);
  u16* o = wq + (size_t)m * DD * DD + i;
  float a = fminf(1.f, fmaxf(-1.f, rintf(v.x / ws)));
  float b = fminf(1.f, fmaxf(-1.f, rintf(v.y / ws)));
  float c = fminf(1.f, fmaxf(-1.f, rintf(v.z / ws)));
  float d = fminf(1.f, fmaxf(-1.f, rintf(v.w / ws)));
  ushort4 pk;
  pk.x = f2bf(a); pk.y = f2bf(b); pk.z = f2bf(c); pk.w = f2bf(d);
  *(ushort4*)o = pk;
}

// ---------------- per-token absmax + inv scale ------------------------------
__global__ void k_rowamax(const float* __restrict__ x, float* __restrict__ amax,
                          float* __restrict__ sinv) {
  int row = blockIdx.x;
  const float* p = x + (size_t)row * DD;
  float m = 0.f;
  for (int i = threadIdx.x * 4; i < DD; i += 1024) {
    float4 v = *(const float4*)(p + i);
    m = fmaxf(m, fmaxf(fmaxf(fabsf(v.x), fabsf(v.y)), fmaxf(fabsf(v.z), fabsf(v.w))));
  }
  m = fmaxf(m, __shfl_xor(m, 1));  m = fmaxf(m, __shfl_xor(m, 2));
  m = fmaxf(m, __shfl_xor(m, 4));  m = fmaxf(m, __shfl_xor(m, 8));
  m = fmaxf(m, __shfl_xor(m, 16)); m = fmaxf(m, __shfl_xor(m, 32));
  __shared__ float red[4];
  if ((threadIdx.x & 63) == 0) red[threadIdx.x >> 6] = m;
  __syncthreads();
  if (threadIdx.x == 0) {
    m = fmaxf(fmaxf(red[0], red[1]), fmaxf(red[2], red[3]));
    m = fmaxf(m, 1e-8f);            // clip(amax, 1e-8)
    amax[row] = m;
    sinv[row] = 127.0f / m;         // matches ref: QMAX / a_max
  }
}

// ---------------- int8-range activation quant -> bf16 -----------------------
__global__ void k_aquant(const float* __restrict__ x, u16* __restrict__ xq,
                         const float* __restrict__ sinv) {
  size_t i = ((size_t)blockIdx.x * 256 + threadIdx.x) * 4;
  int row = (int)(i >> 11);  // /2048
  float s = sinv[row];
  float4 v = *(const float4*)(x + i);
  float a = fminf(127.f, fmaxf(-127.f, rintf(v.x * s)));
  float b = fminf(127.f, fmaxf(-127.f, rintf(v.y * s)));
  float c = fminf(127.f, fmaxf(-127.f, rintf(v.z * s)));
  float d = fminf(127.f, fmaxf(-127.f, rintf(v.w * s)));
  ushort4 pk;
  pk.x = f2bf(a); pk.y = f2bf(b); pk.z = f2bf(c); pk.w = f2bf(d);
  *(ushort4*)(xq + i) = pk;
}

// ---------------- bf16 MFMA GEMM: C[m][n] = sum_k A[m][k]*Bw[n][k] ----------
// 128x128 tile, BK=64, 4 waves (2x2), padded LDS stride 72 (2-way conflicts).
// Epilogue: y * (w_scale * amax[row] / 127); out bf16 (qkv) or f32 (final).
template<bool OB>
__global__ __launch_bounds__(256) void k_gemm(const u16* __restrict__ A, const u16* __restrict__ Bw,
                                              const float* __restrict__ amax,
                                              const float* __restrict__ scales, int sbase,
                                              void* __restrict__ outv) {
  const int LT = 72;
  __shared__ u16 As[128 * 72];
  __shared__ u16 Bs[128 * 72];
  int bm = blockIdx.x, bn = blockIdx.y, mz = blockIdx.z;
  const u16* Bm = Bw + (size_t)mz * DD * DD;
  float wsc = scales[sbase + mz];
  int t = threadIdx.x, w = t >> 6, l = t & 63;
  int wr = w >> 1, wc = w & 1;
  int l15 = l & 15, lh = l >> 4;
  int sr = t >> 3, scol = (t & 7) * 8;
  f32x4 acc[4][4] = {};
  for (int kb = 0; kb < DD / 64; kb++) {
    #pragma unroll
    for (int p = 0; p < 4; p++) {
      int r = p * 32 + sr;
      *(int4*)(As + r * LT + scol) = *(const int4*)(A  + (size_t)(bm * 128 + r) * DD + kb * 64 + scol);
      *(int4*)(Bs + r * LT + scol) = *(const int4*)(Bm + (size_t)(bn * 128 + r) * DD + kb * 64 + scol);
    }
    __syncthreads();
    #pragma unroll
    for (int ks = 0; ks < 2; ks++) {
      bf16x8 af[4], bfr[4];
      #pragma unroll
      for (int i = 0; i < 4; i++)
        af[i] = *(const bf16x8*)(As + (wr * 64 + i * 16 + l15) * LT + ks * 32 + lh * 8);
      #pragma unroll
      for (int j = 0; j < 4; j++)
        bfr[j] = *(const bf16x8*)(Bs + (wc * 64 + j * 16 + l15) * LT + ks * 32 + lh * 8);
      #pragma unroll
      for (int i = 0; i < 4; i++)
        #pragma unroll
        for (int j = 0; j < 4; j++)
          acc[i][j] = MFMA(af[i], bfr[j], acc[i][j]);
    }
    __syncthreads();
  }
  #pragma unroll
  for (int i = 0; i < 4; i++) {
    int row0 = bm * 128 + wr * 64 + i * 16 + lh * 4;
    #pragma unroll
    for (int r = 0; r < 4; r++) {
      float sc = (wsc * amax[row0 + r]) / 127.0f;
      #pragma unroll
      for (int j = 0; j < 4; j++) {
        int col = bn * 128 + wc * 64 + j * 16 + l15;
        float y = acc[i][j][r] * sc;
        if (OB) ((u16*)outv + (size_t)mz * MM * DD)[(size_t)(row0 + r) * DD + col] = f2bf(y);
        else    ((float*)outv)[(size_t)(row0 + r) * DD + col] = y;
      }
    }
  }
}

// ---------------- V transpose: v[b*S+s][h*128+d] -> vt[(b*16+h)*128+d][s] ---
__global__ __launch_bounds__(256) void k_vtrans(const u16* __restrict__ v, u16* __restrict__ vt) {
  __shared__ u16 tile[64][72];
  int sb = blockIdx.x;           // S/64
  int db = blockIdx.y;           // HD/64
  int bh = blockIdx.z;           // B*H
  int b = bh >> 4, h = bh & 15;
  int t = threadIdx.x;
  int ls = t >> 2, ld0 = (t & 3) * 16;
  const u16* src = v + (size_t)(b * SS + sb * 64 + ls) * DD + h * HDD + db * 64 + ld0;
  *(int4*)(&tile[ls][ld0])     = *(const int4*)(src);
  *(int4*)(&tile[ls][ld0 + 8]) = *(const int4*)(src + 8);
  __syncthreads();
  int d = t >> 2, s0 = (t & 3) * 16;
  ushort8_t: ;
  u16 tmp[16];
  #pragma unroll
  for (int k = 0; k < 16; k++) tmp[k] = tile[s0 + k][d];
  u16* dst = vt + (size_t)((bh * HDD) + db * 64 + d) * SS + sb * 64 + s0;
  *(int4*)(dst)     = *(const int4*)(tmp);
  *(int4*)(dst + 8) = *(const int4*)(tmp + 8);
}

// ---------------- causal flash attention, 1 wave / 16 q-rows ----------------
// No barriers: K and V^T fragments read straight from global (L1/L2-resident),
// P routed through per-block LDS (wave-local). Grid: 4096 one-wave blocks,
// XCD-swizzled so each XCD's L2 holds 4 heads' K+V^T (4 MB).
__global__ __launch_bounds__(64) void k_attn(const u16* __restrict__ Q, const u16* __restrict__ K,
                                             const u16* __restrict__ VT, float* __restrict__ O) {
  const int LPT = 72;
  __shared__ u16 Ps[16 * 72];
  int id = blockIdx.x;
  int orig = ((id & 7) << 9) | (id >> 3);   // bijective: XCD x -> heads 4x..4x+3
  int g = orig & 127, bh = orig >> 7;
  int b = bh >> 4, h = bh & 15;
  int l = threadIdx.x, l15 = l & 15, lh = l >> 4;
  size_t base = (size_t)(b * SS) * DD + h * HDD;
  const u16* vtb = VT + (size_t)bh * HDD * SS;
  bf16x8 qf[4];
  {
    const u16* qp = Q + base + (size_t)(g * 16 + l15) * DD + lh * 8;
    #pragma unroll
    for (int kt = 0; kt < 4; kt++) qf[kt] = *(const bf16x8*)(qp + kt * 32);
  }
  f32x4 cacc[8] = {};
  float mrun[4], lrun[4];
  #pragma unroll
  for (int r = 0; r < 4; r++) { mrun[r] = -INFINITY; lrun[r] = 0.f; }
  const float sc = 0.08838834764831845f;  // 1/sqrt(128)
  int ktmax = g >> 2;
  for (int kb = 0; kb <= ktmax; kb++) {
    // S = Q K^T : B-frags straight from global K (row-major [s][d])
    f32x4 sf[4] = {};
    #pragma unroll
    for (int nt = 0; nt < 4; nt++) {
      const u16* kr = K + base + (size_t)(kb * 64 + nt * 16 + l15) * DD + lh * 8;
      #pragma unroll
      for (int kt = 0; kt < 4; kt++) {
        bf16x8 kf = *(const bf16x8*)(kr + kt * 32);
        sf[nt] = MFMA(qf[kt], kf, sf[nt]);
      }
    }
    // scale + causal mask (only the diagonal tile needs masking)
    bool diag = (kb == ktmax);
    #pragma unroll
    for (int nt = 0; nt < 4; nt++) {
      #pragma unroll
      for (int r = 0; r < 4; r++) {
        float v = sf[nt][r] * sc;
        if (diag && (kb * 64 + nt * 16 + l15) > (g * 16 + lh * 4 + r)) v = -1e30f;
        sf[nt][r] = v;
      }
    }
    // online softmax: rows live across the 16 l15-lanes of each lh group
    #pragma unroll
    for (int r = 0; r < 4; r++) {
      float mx = fmaxf(fmaxf(sf[0][r], sf[1][r]), fmaxf(sf[2][r], sf[3][r]));
      mx = fmaxf(mx, __shfl_xor(mx, 1)); mx = fmaxf(mx, __shfl_xor(mx, 2));
      mx = fmaxf(mx, __shfl_xor(mx, 4)); mx = fmaxf(mx, __shfl_xor(mx, 8));
      float mnew = fmaxf(mrun[r], mx);
      float alpha = __expf(mrun[r] - mnew);
      float s0 = 0.f;
      #pragma unroll
      for (int nt = 0; nt < 4; nt++) { float pv = __expf(sf[nt][r] - mnew); sf[nt][r] = pv; s0 += pv; }
      s0 += __shfl_xor(s0, 1); s0 += __shfl_xor(s0, 2);
      s0 += __shfl_xor(s0, 4); s0 += __shfl_xor(s0, 8);
      lrun[r] = lrun[r] * alpha + s0;
      mrun[r] = mnew;
      #pragma unroll
      for (int n2 = 0; n2 < 8; n2++) cacc[n2][r] *= alpha;
    }
    // P -> LDS (C-layout -> A-layout), wave-local so no barrier needed
    #pragma unroll
    for (int r = 0; r < 4; r++)
      #pragma unroll
      for (int nt = 0; nt < 4; nt++)
        Ps[(lh * 4 + r) * LPT + nt * 16 + l15] = f2bf(sf[nt][r]);
    // PV: V^T fragments straight from global (row d, contiguous s)
    #pragma unroll
    for (int ks = 0; ks < 2; ks++) {
      bf16x8 pf = *(const bf16x8*)(Ps + l15 * LPT + ks * 32 + lh * 8);
      #pragma unroll
      for (int n2 = 0; n2 < 8; n2++) {
        bf16x8 vf = *(const bf16x8*)(vtb + (size_t)(n2 * 16 + l15) * SS + kb * 64 + ks * 32 + lh * 8);
        cacc[n2] = MFMA(pf, vf, cacc[n2]);
      }
    }
  }
  #pragma unroll
  for (int r = 0; r < 4; r++) {
    float inv = 1.0f / lrun[r];
    float* op = O + base + (size_t)(g * 16 + lh * 4 + r) * DD;
    #pragma unroll
    for (int n2 = 0; n2 < 8; n2++) op[n2 * 16 + l15] = cacc[n2][r] * inv;
  }
}

// ---------------- launch ----------------------------------------------------
// ws layout (bytes), total ~134.4 MB:
//   0        scales (4 f32)        256      partials (1024 f64)
//   16384    amax_x   32768 sinv_x   49152 amax_ctx   65536 sinv_ctx
//   131072   w_q bf16 (4 x D*D)  = 33,554,432
//   33685504 x_q bf16 (M*D)      = 16,777,216   (reused as V^T, then ctx_q)
//   50462720 q bf16 | 67239936 k | 84017152 v   (16,777,216 each)
//   100794368 ctx f32            = 33,554,432
extern "C" void kernel_launch(void* const* d_in, const int* in_sizes, int n_in,
                              void* d_out, int out_size, void* d_ws, size_t ws_size,
                              hipStream_t stream) {
  const float* x  = (const float*)d_in[0];
  const float* wq = (const float*)d_in[1];
  const float* wk = (const float*)d_in[2];
  const float* wv = (const float*)d_in[3];
  const float* wo = (const float*)d_in[4];
  char* ws = (char*)d_ws;
  float*  scales = (float*)(ws + 0);
  double* part   = (double*)(ws + 256);
  float*  amaxx  = (float*)(ws + 16384);
  float*  sxinv  = (float*)(ws + 32768);
  float*  amaxc  = (float*)(ws + 49152);
  float*  scinv  = (float*)(ws + 65536);
  u16*    wqq    = (u16*)(ws + 131072);
  u16*    xq     = (u16*)(ws + 33685504);   // reused as V^T, then ctx_q
  u16*    qb     = (u16*)(ws + 50462720);
  u16*    kb     = (u16*)(ws + 67239936);
  u16*    vb     = (u16*)(ws + 84017152);
  float*  ctx    = (float*)(ws + 100794368);
  (void)in_sizes; (void)n_in; (void)out_size; (void)ws_size;

  k_wabs_partial<<<1024, 256, 0, stream>>>(wq, wk, wv, wo, part);
  k_wscale_final<<<1, 64, 0, stream>>>(part, scales);
  k_wquant<<<dim3(4096, 4), 256, 0, stream>>>(wq, wk, wv, wo, wqq, scales);
  k_rowamax<<<MM, 256, 0, stream>>>(x, amaxx, sxinv);
  k_aquant<<<8192, 256, 0, stream>>>(x, xq, sxinv);
  // q,k,v projections: out buffers are contiguous -> one launch, grid.z=3
  k_gemm<true><<<dim3(32, 16, 3), 256, 0, stream>>>(xq, wqq, amaxx, scales, 0, (void*)qb);
  // V^T into the (now dead) xq region; then barrier-free flash attention
  k_vtrans<<<dim3(32, 2, 32), 256, 0, stream>>>(vb, xq);
  k_attn<<<4096, 64, 0, stream>>>(qb, kb, xq, ctx);
  k_rowamax<<<MM, 256, 0, stream>>>(ctx, amaxc, scinv);
  k_aquant<<<8192, 256, 0, stream>>>(ctx, xq, scinv);  // ctx_q overwrites V^T (attn done)
  k_gemm<false><<<dim3(32, 16, 1), 256, 0, stream>>>(xq, wqq + (size_t)3 * DD * DD, amaxc, scales, 3, d_out);
}

// Round 3
// 352.220 us; speedup vs baseline: 1.9797x; 1.5256x over previous
//
#include <hip/hip_runtime.h>
#include <hip/hip_bf16.h>
#include <cstdint>
#include <cstddef>

// BitNet b1.58 attention block: B=2 S=2048 D=2048 H=16 HD=128.
// All quantized matmuls done in bf16 MFMA (exact: int8 x ternary, sums < 2^24).

#define BB 2
#define SS 2048
#define DD 2048
#define HH 16
#define HDD 128
#define MM (BB*SS)   // 4096 token rows

typedef __attribute__((ext_vector_type(8))) short bf16x8;
typedef __attribute__((ext_vector_type(4))) float f32x4;
typedef unsigned short u16;
typedef unsigned int   u32;

#define MFMA(a,b,c) __builtin_amdgcn_mfma_f32_16x16x32_bf16(a,b,c,0,0,0)

static __device__ __forceinline__ u16 f2bf(float f) {
  // round-to-nearest-even float->bf16 (no NaN inputs here)
  u32 x = __float_as_uint(f);
  u32 r = x + 0x7fffu + ((x >> 16) & 1u);
  return (u16)(r >> 16);
}

// async global->LDS, 16B per lane; LDS dest must be linear (base + lane*16)
static __device__ __forceinline__ void gl_lds16(const u16* g, u16* l) {
  __builtin_amdgcn_global_load_lds((const __attribute__((address_space(1))) void*)g,
                                   (__attribute__((address_space(3))) void*)l, 16, 0, 0);
}

// ---------------- weight scale: deterministic two-stage |w| mean in f64 ----
__global__ void k_wabs_partial(const float* __restrict__ w0, const float* __restrict__ w1,
                               const float* __restrict__ w2, const float* __restrict__ w3,
                               double* __restrict__ part) {
  int m = blockIdx.x >> 8, blk = blockIdx.x & 255;
  const float* w = (m == 0) ? w0 : (m == 1) ? w1 : (m == 2) ? w2 : w3;
  const float* p = w + (size_t)blk * 16384;
  double s = 0.0;
  for (int i = threadIdx.x * 4; i < 16384; i += 1024) {
    float4 v = *(const float4*)(p + i);
    s += (double)fabsf(v.x) + (double)fabsf(v.y) + (double)fabsf(v.z) + (double)fabsf(v.w);
  }
  __shared__ double red[256];
  red[threadIdx.x] = s;
  __syncthreads();
  for (int off = 128; off > 0; off >>= 1) {
    if ((int)threadIdx.x < off) red[threadIdx.x] += red[threadIdx.x + off];
    __syncthreads();
  }
  if (threadIdx.x == 0) part[m * 256 + blk] = red[0];
}

__global__ void k_wscale_final(const double* __restrict__ part, float* __restrict__ scales) {
  int m = threadIdx.x;
  if (m < 4) {
    double s = 0.0;
    for (int i = 0; i < 256; i++) s += part[m * 256 + i];
    float v = (float)(s * (1.0 / 4194304.0));   // /(D*D), power of 2: exact
    scales[m] = fmaxf(v, 1e-6f);
  }
}

// ---------------- ternary weight quant -> bf16 ------------------------------
__global__ void k_wquant(const float* __restrict__ w0, const float* __restrict__ w1,
                         const float* __restrict__ w2, const float* __restrict__ w3,
                         u16* __restrict__ wq, const float* __restrict__ scales) {
  int m = blockIdx.y;
  const float* w = (m == 0) ? w0 : (m == 1) ? w1 : (m == 2) ? w2 : w3;
  float ws = scales[m];
  size_t i = ((size_t)blockIdx.x * 256 + threadIdx.x) * 4;
  float4 v = *(const float4*)(w + i);
  u16* o = wq + (size_t)m * DD * DD + i;
  float a = fminf(1.f, fmaxf(-1.f, rintf(v.x / ws)));
  float b = fminf(1.f, fmaxf(-1.f, rintf(v.y / ws)));
  float c = fminf(1.f, fmaxf(-1.f, rintf(v.z / ws)));
  float d = fminf(1.f, fmaxf(-1.f, rintf(v.w / ws)));
  ushort4 pk;
  pk.x = f2bf(a); pk.y = f2bf(b); pk.z = f2bf(c); pk.w = f2bf(d);
  *(ushort4*)o = pk;
}

// ---------------- per-token absmax + inv scale ------------------------------
__global__ void k_rowamax(const float* __restrict__ x, float* __restrict__ amax,
                          float* __restrict__ sinv) {
  int row = blockIdx.x;
  const float* p = x + (size_t)row * DD;
  float m = 0.f;
  for (int i = threadIdx.x * 4; i < DD; i += 1024) {
    float4 v = *(const float4*)(p + i);
    m = fmaxf(m, fmaxf(fmaxf(fabsf(v.x), fabsf(v.y)), fmaxf(fabsf(v.z), fabsf(v.w))));
  }
  m = fmaxf(m, __shfl_xor(m, 1));  m = fmaxf(m, __shfl_xor(m, 2));
  m = fmaxf(m, __shfl_xor(m, 4));  m = fmaxf(m, __shfl_xor(m, 8));
  m = fmaxf(m, __shfl_xor(m, 16)); m = fmaxf(m, __shfl_xor(m, 32));
  __shared__ float red[4];
  if ((threadIdx.x & 63) == 0) red[threadIdx.x >> 6] = m;
  __syncthreads();
  if (threadIdx.x == 0) {
    m = fmaxf(fmaxf(red[0], red[1]), fmaxf(red[2], red[3]));
    m = fmaxf(m, 1e-8f);            // clip(amax, 1e-8)
    amax[row] = m;
    sinv[row] = 127.0f / m;         // matches ref: QMAX / a_max
  }
}

// ---------------- int8-range activation quant -> bf16 -----------------------
__global__ void k_aquant(const float* __restrict__ x, u16* __restrict__ xq,
                         const float* __restrict__ sinv) {
  size_t i = ((size_t)blockIdx.x * 256 + threadIdx.x) * 4;
  int row = (int)(i >> 11);  // /2048
  float s = sinv[row];
  float4 v = *(const float4*)(x + i);
  float a = fminf(127.f, fmaxf(-127.f, rintf(v.x * s)));
  float b = fminf(127.f, fmaxf(-127.f, rintf(v.y * s)));
  float c = fminf(127.f, fmaxf(-127.f, rintf(v.z * s)));
  float d = fminf(127.f, fmaxf(-127.f, rintf(v.w * s)));
  ushort4 pk;
  pk.x = f2bf(a); pk.y = f2bf(b); pk.z = f2bf(c); pk.w = f2bf(d);
  *(ushort4*)(xq + i) = pk;
}

// ---------------- bf16 MFMA GEMM: C[m][n] = sum_k A[m][k]*Bw[n][k] ----------
// m97 structure: 128x128 tile, BK=64, 4 waves, global_load_lds width-16 into
// linear LDS with XOR-swizzled 16B blocks (pre-swizzled global source, rule 21).
// Epilogue: y * (w_scale * amax[row] / 127); out bf16 (qkv) or f32 (final).
template<bool OB>
__global__ __launch_bounds__(256) void k_gemm(const u16* __restrict__ A, const u16* __restrict__ Bw,
                                              const float* __restrict__ amax,
                                              const float* __restrict__ scales, int sbase,
                                              void* __restrict__ outv) {
  __shared__ u16 As[128 * 64];
  __shared__ u16 Bs[128 * 64];
  int bm = blockIdx.x, bn = blockIdx.y, mz = blockIdx.z;
  const u16* Bm = Bw + (size_t)mz * DD * DD;
  float wsc = scales[sbase + mz];
  int t = threadIdx.x, w = t >> 6, l = t & 63;
  int wr = w >> 1, wc = w & 1;
  int l15 = l & 15, lh = l >> 4;
  // staging slots: inst i covers linear 16B slot s=i*256+t; row=s>>3, blk=t&7;
  // global column block = blk ^ (row&7)  (inverse of the read-side swizzle)
  int srow[4], scol[4];
  #pragma unroll
  for (int i = 0; i < 4; i++) {
    int s = i * 256 + t;
    srow[i] = s >> 3;
    scol[i] = (((t & 7) ^ (srow[i] & 7)) * 8);
  }
  const u16* Ab = A  + (size_t)(bm * 128) * DD;
  const u16* Bb = Bm + (size_t)(bn * 128) * DD;
  f32x4 acc[4][4] = {};
  for (int kb = 0; kb < DD / 64; kb++) {
    #pragma unroll
    for (int i = 0; i < 4; i++) {
      gl_lds16(Ab + (size_t)srow[i] * DD + kb * 64 + scol[i], As + (size_t)(i * 256 + t) * 8);
      gl_lds16(Bb + (size_t)srow[i] * DD + kb * 64 + scol[i], Bs + (size_t)(i * 256 + t) * 8);
    }
    __syncthreads();
    #pragma unroll
    for (int ks = 0; ks < 2; ks++) {
      bf16x8 af[4], bfr[4];
      #pragma unroll
      for (int i = 0; i < 4; i++)
        af[i] = *(const bf16x8*)(As + (wr * 64 + i * 16 + l15) * 64 + (((ks * 4 + lh) ^ (l15 & 7)) * 8));
      #pragma unroll
      for (int j = 0; j < 4; j++)
        bfr[j] = *(const bf16x8*)(Bs + (wc * 64 + j * 16 + l15) * 64 + (((ks * 4 + lh) ^ (l15 & 7)) * 8));
      #pragma unroll
      for (int i = 0; i < 4; i++)
        #pragma unroll
        for (int j = 0; j < 4; j++)
          acc[i][j] = MFMA(af[i], bfr[j], acc[i][j]);
    }
    __syncthreads();
  }
  #pragma unroll
  for (int i = 0; i < 4; i++) {
    int row0 = bm * 128 + wr * 64 + i * 16 + lh * 4;
    #pragma unroll
    for (int r = 0; r < 4; r++) {
      float sc = (wsc * amax[row0 + r]) / 127.0f;
      #pragma unroll
      for (int j = 0; j < 4; j++) {
        int col = bn * 128 + wc * 64 + j * 16 + l15;
        float y = acc[i][j][r] * sc;
        if (OB) ((u16*)outv + (size_t)mz * MM * DD)[(size_t)(row0 + r) * DD + col] = f2bf(y);
        else    ((float*)outv)[(size_t)(row0 + r) * DD + col] = y;
      }
    }
  }
}

// ---------------- V transpose: v[b*S+s][h*128+d] -> vt[(b*16+h)*128+d][s] ---
__global__ __launch_bounds__(256) void k_vtrans(const u16* __restrict__ v, u16* __restrict__ vt) {
  __shared__ u16 tile[64][72];
  int sb = blockIdx.x;           // S/64
  int db = blockIdx.y;           // HD/64
  int bh = blockIdx.z;           // B*H
  int b = bh >> 4, h = bh & 15;
  int t = threadIdx.x;
  int ls = t >> 2, ld0 = (t & 3) * 16;
  const u16* src = v + (size_t)(b * SS + sb * 64 + ls) * DD + h * HDD + db * 64 + ld0;
  *(int4*)(&tile[ls][ld0])     = *(const int4*)(src);
  *(int4*)(&tile[ls][ld0 + 8]) = *(const int4*)(src + 8);
  __syncthreads();
  int d = t >> 2, s0 = (t & 3) * 16;
  u16 tmp[16];
  #pragma unroll
  for (int k = 0; k < 16; k++) tmp[k] = tile[s0 + k][d];
  u16* dst = vt + (size_t)((bh * HDD) + db * 64 + d) * SS + sb * 64 + s0;
  *(int4*)(dst)     = *(const int4*)(tmp);
  *(int4*)(dst + 8) = *(const int4*)(tmp + 8);
}

// ---------------- causal flash attention ------------------------------------
// 4 waves x 16 q-rows (QBLK=64), KVBLK=64. K-tile + V^T-tile staged via
// global_load_lds into linear LDS with XOR-swizzled 16B blocks; fragments via
// conflict-free ds_read_b128. P routed through per-wave padded LDS.
// Grid: 1024 blocks, XCD-swizzled (4 heads per XCD's L2).
__global__ __launch_bounds__(256) void k_attn(const u16* __restrict__ Q, const u16* __restrict__ K,
                                              const u16* __restrict__ VT, float* __restrict__ O) {
  __shared__ u16 Ks[64 * 128];   // [s][d]  256B rows, swizzled blocks
  __shared__ u16 Vs[128 * 64];   // [d][s]  128B rows, swizzled blocks
  __shared__ u16 Ps[4 * 16 * 72];
  int id = blockIdx.x;
  int orig = ((id & 7) << 7) | (id >> 3);   // bijective: XCD x -> bh 4x..4x+3
  int qb = orig & 31, bh = orig >> 5;
  int b = bh >> 4, h = bh & 15;
  int t = threadIdx.x, w = t >> 6, l = t & 63;
  int l15 = l & 15, lh = l >> 4;
  size_t base = (size_t)(b * SS) * DD + h * HDD;
  const u16* vtb = VT + (size_t)bh * HDD * SS;
  u16* Pw = Ps + w * 16 * 72;
  bf16x8 qf[4];
  {
    const u16* qp = Q + base + (size_t)(qb * 64 + w * 16 + l15) * DD + lh * 8;
    #pragma unroll
    for (int kt = 0; kt < 4; kt++) qf[kt] = *(const bf16x8*)(qp + kt * 32);
  }
  f32x4 cacc[8] = {};
  float mrun[4], lrun[4];
  #pragma unroll
  for (int r = 0; r < 4; r++) { mrun[r] = -INFINITY; lrun[r] = 0.f; }
  const float sc = 0.08838834764831845f;  // 1/sqrt(128)
  // staging slots (K: 16 blocks/row; VT: 8 blocks/row), source pre-swizzled
  int ksr[4], ksc[4], vsr[4], vsc[4];
  #pragma unroll
  for (int i = 0; i < 4; i++) {
    int s = i * 256 + t;
    ksr[i] = s >> 4; ksc[i] = (((t & 15) ^ (ksr[i] & 7)) * 8);
    vsr[i] = s >> 3; vsc[i] = (((t & 7)  ^ (vsr[i] & 7)) * 8);
  }
  for (int kb = 0; kb <= qb; kb++) {
    #pragma unroll
    for (int i = 0; i < 4; i++) {
      gl_lds16(K + base + (size_t)(kb * 64 + ksr[i]) * DD + ksc[i], Ks + (size_t)(i * 256 + t) * 8);
      gl_lds16(vtb + (size_t)vsr[i] * SS + kb * 64 + vsc[i],        Vs + (size_t)(i * 256 + t) * 8);
    }
    __syncthreads();
    // S = Q K^T : B-frags from swizzled Ks
    f32x4 sf[4] = {};
    #pragma unroll
    for (int nt = 0; nt < 4; nt++) {
      #pragma unroll
      for (int kt = 0; kt < 4; kt++) {
        bf16x8 kf = *(const bf16x8*)(Ks + (nt * 16 + l15) * 128 + (((kt * 4 + lh) ^ (l15 & 7)) * 8));
        sf[nt] = MFMA(qf[kt], kf, sf[nt]);
      }
    }
    // scale + causal mask (only the diagonal tile needs masking)
    bool diag = (kb == qb);
    #pragma unroll
    for (int nt = 0; nt < 4; nt++) {
      #pragma unroll
      for (int r = 0; r < 4; r++) {
        float v = sf[nt][r] * sc;
        if (diag && (nt * 16 + l15) > (w * 16 + lh * 4 + r)) v = -1e30f;
        sf[nt][r] = v;
      }
    }
    // online softmax: rows live across the 16 l15-lanes of each lh group
    #pragma unroll
    for (int r = 0; r < 4; r++) {
      float mx = fmaxf(fmaxf(sf[0][r], sf[1][r]), fmaxf(sf[2][r], sf[3][r]));
      mx = fmaxf(mx, __shfl_xor(mx, 1)); mx = fmaxf(mx, __shfl_xor(mx, 2));
      mx = fmaxf(mx, __shfl_xor(mx, 4)); mx = fmaxf(mx, __shfl_xor(mx, 8));
      float mnew = fmaxf(mrun[r], mx);
      float alpha = __expf(mrun[r] - mnew);
      float s0 = 0.f;
      #pragma unroll
      for (int nt = 0; nt < 4; nt++) { float pv = __expf(sf[nt][r] - mnew); sf[nt][r] = pv; s0 += pv; }
      s0 += __shfl_xor(s0, 1); s0 += __shfl_xor(s0, 2);
      s0 += __shfl_xor(s0, 4); s0 += __shfl_xor(s0, 8);
      lrun[r] = lrun[r] * alpha + s0;
      mrun[r] = mnew;
      #pragma unroll
      for (int n2 = 0; n2 < 8; n2++) cacc[n2][r] *= alpha;
    }
    // P -> per-wave LDS (C-layout -> A-layout), then PV from swizzled Vs
    #pragma unroll
    for (int r = 0; r < 4; r++)
      #pragma unroll
      for (int nt = 0; nt < 4; nt++)
        Pw[(lh * 4 + r) * 72 + nt * 16 + l15] = f2bf(sf[nt][r]);
    #pragma unroll
    for (int ks = 0; ks < 2; ks++) {
      bf16x8 pf = *(const bf16x8*)(Pw + l15 * 72 + ks * 32 + lh * 8);
      #pragma unroll
      for (int n2 = 0; n2 < 8; n2++) {
        bf16x8 vf = *(const bf16x8*)(Vs + (n2 * 16 + l15) * 64 + (((ks * 4 + lh) ^ (l15 & 7)) * 8));
        cacc[n2] = MFMA(pf, vf, cacc[n2]);
      }
    }
    __syncthreads();
  }
  #pragma unroll
  for (int r = 0; r < 4; r++) {
    float inv = 1.0f / lrun[r];
    float* op = O + base + (size_t)(qb * 64 + w * 16 + lh * 4 + r) * DD;
    #pragma unroll
    for (int n2 = 0; n2 < 8; n2++) op[n2 * 16 + l15] = cacc[n2][r] * inv;
  }
}

// ---------------- launch ----------------------------------------------------
// ws layout (bytes), total ~134.4 MB:
//   0        scales (4 f32)        256      partials (1024 f64)
//   16384    amax_x   32768 sinv_x   49152 amax_ctx   65536 sinv_ctx
//   131072   w_q bf16 (4 x D*D)  = 33,554,432
//   33685504 x_q bf16 (M*D)      = 16,777,216   (reused as V^T, then ctx_q)
//   50462720 q bf16 | 67239936 k | 84017152 v   (16,777,216 each)
//   100794368 ctx f32            = 33,554,432
extern "C" void kernel_launch(void* const* d_in, const int* in_sizes, int n_in,
                              void* d_out, int out_size, void* d_ws, size_t ws_size,
                              hipStream_t stream) {
  const float* x  = (const float*)d_in[0];
  const float* wq = (const float*)d_in[1];
  const float* wk = (const float*)d_in[2];
  const float* wv = (const float*)d_in[3];
  const float* wo = (const float*)d_in[4];
  char* ws = (char*)d_ws;
  float*  scales = (float*)(ws + 0);
  double* part   = (double*)(ws + 256);
  float*  amaxx  = (float*)(ws + 16384);
  float*  sxinv  = (float*)(ws + 32768);
  float*  amaxc  = (float*)(ws + 49152);
  float*  scinv  = (float*)(ws + 65536);
  u16*    wqq    = (u16*)(ws + 131072);
  u16*    xq     = (u16*)(ws + 33685504);   // reused as V^T, then ctx_q
  u16*    qb     = (u16*)(ws + 50462720);
  u16*    kb     = (u16*)(ws + 67239936);
  u16*    vb     = (u16*)(ws + 84017152);
  float*  ctx    = (float*)(ws + 100794368);
  (void)in_sizes; (void)n_in; (void)out_size; (void)ws_size;

  k_wabs_partial<<<1024, 256, 0, stream>>>(wq, wk, wv, wo, part);
  k_wscale_final<<<1, 64, 0, stream>>>(part, scales);
  k_wquant<<<dim3(4096, 4), 256, 0, stream>>>(wq, wk, wv, wo, wqq, scales);
  k_rowamax<<<MM, 256, 0, stream>>>(x, amaxx, sxinv);
  k_aquant<<<8192, 256, 0, stream>>>(x, xq, sxinv);
  // q,k,v projections: out buffers are contiguous -> one launch, grid.z=3
  k_gemm<true><<<dim3(32, 16, 3), 256, 0, stream>>>(xq, wqq, amaxx, scales, 0, (void*)qb);
  // V^T into the (now dead) xq region; then LDS-staged flash attention
  k_vtrans<<<dim3(32, 2, 32), 256, 0, stream>>>(vb, xq);
  k_attn<<<1024, 256, 0, stream>>>(qb, kb, xq, ctx);
  k_rowamax<<<MM, 256, 0, stream>>>(ctx, amaxc, scinv);
  k_aquant<<<8192, 256, 0, stream>>>(ctx, xq, scinv);  // ctx_q overwrites V^T (attn done)
  k_gemm<false><<<dim3(32, 16, 1), 256, 0, stream>>>(xq, wqq + (size_t)3 * DD * DD, amaxc, scales, 3, d_out);
}